// Round 4
// baseline (1002.476 us; speedup 1.0000x reference)
//
#include <hip/hip_runtime.h>
#include <hip/hip_bf16.h>

#define N_NODES  50000
#define N_EDGES  800000
#define NDIM_IN  64
#define EDIMS    64
#define NDIM_OUT 128

#define NPB      64                      // nodes per bucket
#define NB       ((N_NODES + NPB - 1) / NPB)   // 782 buckets
#define SENTINEL 0x80000000u             // local=64 (dummy LDS row), eid=0

typedef __bf16 bf16;
typedef bf16  bf16x8 __attribute__((ext_vector_type(8)));
typedef float f32x4  __attribute__((ext_vector_type(4)));

// ---------------------------------------------------------------------------
// dtype detection (floats are fp32 per round-1 evidence; indices int32/int64
// ambiguous -> detect per block, ~64 scalar loads)
// ---------------------------------------------------------------------------
__device__ __forceinline__ bool detect_f32(const void* nfeats) {
    const unsigned short* w = (const unsigned short*)nfeats;
    for (int i = 0; i < 64; i += 2) {
        const int e = (w[i] >> 7) & 0xFF;
        if (e < 100 || e > 134) return true;   // bf16 N(0,1) exps live in [100,134]
    }
    return false;
}
__device__ __forceinline__ bool detect_i64(const int* p) {
    for (int i = 1; i < 64; i += 2) if (p[i] != 0) return false;
    return true;
}
__device__ __forceinline__ bf16x8 load8(const void* p, int off, bool f32) {
    if (f32) {
        const float* q = (const float*)p + off;
        const f32x4 a = *(const f32x4*)q;
        const f32x4 b = *(const f32x4*)(q + 4);
        bf16x8 r;
        #pragma unroll
        for (int u = 0; u < 4; ++u) { r[u] = (bf16)a[u]; r[4 + u] = (bf16)b[u]; }
        return r;
    }
    return *(const bf16x8*)((const bf16*)p + off);
}
__device__ __forceinline__ float loadf(const void* p, int i, bool f32) {
    return f32 ? ((const float*)p)[i] : (float)((const bf16*)p)[i];
}
__device__ __forceinline__ void storef(void* p, int i, float v, bool f32) {
    if (f32) ((float*)p)[i] = v; else ((bf16*)p)[i] = (bf16)v;
}

// ---------------------------------------------------------------------------
// K1: histogram of dst into NB buckets (bucket = node >> 6)
// ---------------------------------------------------------------------------
__global__ __launch_bounds__(256) void hist_kernel(
    const int* __restrict__ dst, int* __restrict__ count)
{
    __shared__ int s_ish;
    if (threadIdx.x == 0) s_ish = detect_i64(dst) ? 1 : 0;
    __syncthreads();
    const int ish = s_ish;
    for (int e = blockIdx.x * 256 + threadIdx.x; e < N_EDGES; e += gridDim.x * 256)
        atomicAdd(&count[dst[e << ish] >> 6], 1);
}

// ---------------------------------------------------------------------------
// K2: exclusive scan of 1024 counts (NB=782 real, rest zero) -> starts, cursor
// ---------------------------------------------------------------------------
__global__ __launch_bounds__(1024) void scan_kernel(
    const int* __restrict__ count, int* __restrict__ starts, int* __restrict__ cursor)
{
    __shared__ int s[1024];
    const int tid = threadIdx.x;
    const int own = (tid < NB) ? count[tid] : 0;
    s[tid] = own;
    __syncthreads();
    for (int off = 1; off < 1024; off <<= 1) {
        int t = (tid >= off) ? s[tid - off] : 0;
        __syncthreads();
        s[tid] += t;
        __syncthreads();
    }
    const int excl = s[tid] - own;
    starts[tid] = excl;
    if (tid < NB) cursor[tid] = excl;
}

// ---------------------------------------------------------------------------
// K3: scatter edges into dst-bucketed order; pack eid(20b) | local(7b @ bit25)
// ---------------------------------------------------------------------------
__global__ __launch_bounds__(256) void scatter_kernel(
    const int* __restrict__ dst, int* __restrict__ cursor,
    unsigned* __restrict__ sorted)
{
    __shared__ int s_ish;
    if (threadIdx.x == 0) s_ish = detect_i64(dst) ? 1 : 0;
    __syncthreads();
    const int ish = s_ish;
    for (int e = blockIdx.x * 256 + threadIdx.x; e < N_EDGES; e += gridDim.x * 256) {
        const int d = dst[e << ish];
        const int pos = atomicAdd(&cursor[d >> 6], 1);
        sorted[pos] = (unsigned)e | ((unsigned)(d & 63) << 25);
    }
}

// ---------------------------------------------------------------------------
// K4: fused message GEMM + LDS aggregation. One block = one 64-node bucket.
// msg = relu([nfeats[src], efeats] @ W_msg + b_msg)  -> ds_add_f32 into sH.
// MFMA: A=W^T(LDS), B=edge feats -> C col = edge slot, row = out dim.
// sH row stride 133 f32: ds_add banks = (5*row + col) % 32, ~uniform.
// ---------------------------------------------------------------------------
__global__ __launch_bounds__(256) void agg_kernel(
    const void* __restrict__ nfeats,
    const void* __restrict__ efeats,
    const void* __restrict__ W_msg,
    const void* __restrict__ b_msg,
    const int*  __restrict__ src,
    const int*  __restrict__ starts,
    const unsigned* __restrict__ sorted,
    bf16*       __restrict__ h_neigh)
{
    __shared__ float sH[65 * 133];     // 64 node rows + 1 dummy, stride 133
    __shared__ bf16  sWT[128 * 136];   // W_msg^T [n][k], stride 136
    __shared__ float sB[128];
    __shared__ int   s_flags;

    const int tid = threadIdx.x;
    if (tid == 0)
        s_flags = (detect_f32(nfeats) ? 1 : 0) | (detect_i64(src) ? 2 : 0);
    // zero the h slice
    for (int i = tid; i < 65 * 133; i += 256) sH[i] = 0.f;
    __syncthreads();
    const bool f32 = (s_flags & 1) != 0;
    const int  ish = (s_flags & 2) ? 1 : 0;

    #pragma unroll
    for (int it = 0; it < 8; ++it) {   // stage W_msg^T (128x128)
        const int task = it * 256 + tid;
        const int k = task >> 4;
        const int c = task & 15;
        const bf16x8 w = load8(W_msg, k * 128 + c * 8, f32);
        #pragma unroll
        for (int u = 0; u < 8; ++u) sWT[(c * 8 + u) * 136 + k] = w[u];
    }
    if (tid < 128) sB[tid] = loadf(b_msg, tid, f32);
    __syncthreads();

    const int wave = tid >> 6;
    const int lane = tid & 63;
    const int m    = lane & 15;   // edge slot (B col / C col)
    const int quad = lane >> 4;   // k-group / C row group

    const int bkt   = blockIdx.x;
    const int start = starts[bkt];
    const int end   = starts[bkt + 1];

    int i0 = start + wave * 16;
    if (i0 < end) {
        // prologue: meta + features for first group
        int idx = i0 + m;
        unsigned v = (idx < end) ? sorted[idx] : SENTINEL;
        int eid   = v & 0xFFFFF;
        int local = v >> 25;
        int s     = src[eid << ish];
        bf16x8 cf0 = load8(nfeats, s   * 64 +      quad * 8, f32);
        bf16x8 cf1 = load8(nfeats, s   * 64 + 32 + quad * 8, f32);
        bf16x8 cf2 = load8(efeats, eid * 64 +      quad * 8, f32);
        bf16x8 cf3 = load8(efeats, eid * 64 + 32 + quad * 8, f32);

        for (; i0 < end; i0 += 64) {
            // prefetch next group's meta + features (sentinel-safe)
            const int idxn = i0 + 64 + m;
            const unsigned vn = (idxn < end) ? sorted[idxn] : SENTINEL;
            const int eidn   = vn & 0xFFFFF;
            const int localn = vn >> 25;
            const int sn     = src[eidn << ish];
            const bf16x8 nf0 = load8(nfeats, sn   * 64 +      quad * 8, f32);
            const bf16x8 nf1 = load8(nfeats, sn   * 64 + 32 + quad * 8, f32);
            const bf16x8 nf2 = load8(efeats, eidn * 64 +      quad * 8, f32);
            const bf16x8 nf3 = load8(efeats, eidn * 64 + 32 + quad * 8, f32);

            // compute current group
            float* hp = &sH[local * 133];
            #pragma unroll
            for (int t = 0; t < 8; ++t) {
                f32x4 acc = *(const f32x4*)(sB + t * 16 + quad * 4); // bias-init
                const bf16* ap = sWT + (t * 16 + m) * 136 + quad * 8;
                acc = __builtin_amdgcn_mfma_f32_16x16x32_bf16(*(const bf16x8*)(ap      ), cf0, acc, 0, 0, 0);
                acc = __builtin_amdgcn_mfma_f32_16x16x32_bf16(*(const bf16x8*)(ap + 32 ), cf1, acc, 0, 0, 0);
                acc = __builtin_amdgcn_mfma_f32_16x16x32_bf16(*(const bf16x8*)(ap + 64 ), cf2, acc, 0, 0, 0);
                acc = __builtin_amdgcn_mfma_f32_16x16x32_bf16(*(const bf16x8*)(ap + 96 ), cf3, acc, 0, 0, 0);
                #pragma unroll
                for (int i = 0; i < 4; ++i) {
                    const float val = acc[i];
                    if (val > 0.f)
                        atomicAdd(hp + t * 16 + quad * 4 + i, val);  // ds_add_f32
                }
            }
            // rotate buffers
            cf0 = nf0; cf1 = nf1; cf2 = nf2; cf3 = nf3;
            local = localn;
        }
    }
    __syncthreads();

    // write h slice to global as bf16, coalesced (pairs of dims per thread)
    const int base = bkt * NPB;
    for (int i = tid; i < NPB * 64; i += 256) {
        const int lrow  = i >> 6;        // 0..63
        const int dpair = i & 63;        // dword index within 128-dim row
        const int node  = base + lrow;
        if (node < N_NODES) {
            const float f0 = sH[lrow * 133 + 2 * dpair];
            const float f1 = sH[lrow * 133 + 2 * dpair + 1];
            __hip_bfloat162 pv;
            pv.x = __float2bfloat16(f0);
            pv.y = __float2bfloat16(f1);
            *(__hip_bfloat162*)(h_neigh + node * 128 + 2 * dpair) = pv;
        }
    }
}

// ---------------------------------------------------------------------------
// K5: out = relu([nfeats, h_neigh] @ W_apply + b_apply), K=192.
// Grid 256, each block loops ~3 chunks (amortize W staging).
// ---------------------------------------------------------------------------
__global__ __launch_bounds__(256) void apply_kernel(
    const void* __restrict__ nfeats,
    const bf16* __restrict__ h_neigh,
    const void* __restrict__ W_apply,
    const void* __restrict__ b_apply,
    void*       __restrict__ out)
{
    __shared__ bf16  sWT[128 * 200];   // [n][k], k<192, stride 200
    __shared__ float sB[128];
    __shared__ int s_flags;

    const int tid = threadIdx.x;
    if (tid == 0) s_flags = detect_f32(nfeats) ? 1 : 0;
    __syncthreads();
    const bool f32 = (s_flags & 1) != 0;

    #pragma unroll
    for (int it = 0; it < 12; ++it) {   // stage W_apply^T (192x128)
        const int task = it * 256 + tid;
        const int k = task >> 4;
        const int c = task & 15;
        const bf16x8 w = load8(W_apply, k * 128 + c * 8, f32);
        #pragma unroll
        for (int u = 0; u < 8; ++u) sWT[(c * 8 + u) * 200 + k] = w[u];
    }
    if (tid < 128) sB[tid] = loadf(b_apply, tid, f32);
    __syncthreads();

    const int wave = tid >> 6;
    const int lane = tid & 63;
    const int m    = lane & 15;
    const int quad = lane >> 4;

    const int nchunks = (N_NODES + 63) / 64;   // 782
    for (int chunk = blockIdx.x; chunk < nchunks; chunk += gridDim.x) {
        const int nbase = chunk * 64 + wave * 16;
        const int nm  = nbase + m;
        const int nmc = nm < N_NODES ? nm : N_NODES - 1;

        bf16x8 a[6];
        a[0] = load8(nfeats, nmc * 64 +      quad * 8, f32);
        a[1] = load8(nfeats, nmc * 64 + 32 + quad * 8, f32);
        #pragma unroll
        for (int kb = 0; kb < 4; ++kb)
            a[2 + kb] = *(const bf16x8*)(h_neigh + nmc * 128 + kb * 32 + quad * 8);

        #pragma unroll
        for (int t = 0; t < 8; ++t) {
            f32x4 acc = {0.f, 0.f, 0.f, 0.f};
            const bf16* bp = sWT + (t * 16 + m) * 200 + quad * 8;
            #pragma unroll
            for (int kb = 0; kb < 6; ++kb)
                acc = __builtin_amdgcn_mfma_f32_16x16x32_bf16(
                          a[kb], *(const bf16x8*)(bp + kb * 32), acc, 0, 0, 0);
            const int n = t * 16 + m;
            #pragma unroll
            for (int i = 0; i < 4; ++i) {
                const int row = nbase + quad * 4 + i;
                if (row < N_NODES) {
                    float v = acc[i] + sB[n];
                    v = v > 0.f ? v : 0.f;
                    storef(out, row * 128 + n, v, f32);
                }
            }
        }
    }
}

extern "C" void kernel_launch(void* const* d_in, const int* in_sizes, int n_in,
                              void* d_out, int out_size, void* d_ws, size_t ws_size,
                              hipStream_t stream) {
    const void* nfeats  = d_in[0];
    const void* efeats  = d_in[1];
    const void* W_msg   = d_in[2];
    const void* b_msg   = d_in[3];
    const void* W_apply = d_in[4];
    const void* b_apply = d_in[5];
    const int*  src     = (const int*)d_in[6];
    const int*  dst     = (const int*)d_in[7];

    // workspace layout
    char* ws = (char*)d_ws;
    bf16*     h_neigh = (bf16*)ws;                              // 12.8 MB
    int*      count   = (int*)(ws + 12800000);                  // 4 KB (1024 ints)
    int*      starts  = (int*)(ws + 12800000 + 4096);           // 4 KB
    int*      cursor  = (int*)(ws + 12800000 + 8192);           // 4 KB
    unsigned* sorted  = (unsigned*)(ws + 12800000 + 12288);     // 3.2 MB

    hipMemsetAsync(count, 0, 1024 * sizeof(int), stream);

    hist_kernel   <<<256, 256,  0, stream>>>(dst, count);
    scan_kernel   <<<1,   1024, 0, stream>>>(count, starts, cursor);
    scatter_kernel<<<256, 256,  0, stream>>>(dst, cursor, sorted);
    agg_kernel    <<<NB,  256,  0, stream>>>(nfeats, efeats, W_msg, b_msg,
                                             src, starts, sorted, h_neigh);
    apply_kernel  <<<256, 256,  0, stream>>>(nfeats, h_neigh, W_apply, b_apply, d_out);
}

// Round 5
// 688.027 us; speedup vs baseline: 1.4570x; 1.4570x over previous
//
#include <hip/hip_runtime.h>
#include <hip/hip_bf16.h>

#define N_NODES  50000
#define N_EDGES  800000
#define NDIM_IN  64
#define EDIMS    64
#define NDIM_OUT 128

#define NPB   32                                // nodes per bucket
#define NBKT  ((N_NODES + NPB - 1) / NPB)       // 1563 buckets
#define BPAD  2048                              // padded bucket count (scan)
#define SENTM (32u << 25)                       // sentinel meta: local=32 (dummy row), eid=0

typedef __bf16 bf16;
typedef bf16  bf16x8 __attribute__((ext_vector_type(8)));
typedef float f32x4  __attribute__((ext_vector_type(4)));

// ---------------------------------------------------------------------------
// dtype detection helpers (fp32 floats per round-1 evidence; int width ambiguous)
// ---------------------------------------------------------------------------
__device__ __forceinline__ bool detect_f32(const void* nfeats) {
    const unsigned short* w = (const unsigned short*)nfeats;
    for (int i = 0; i < 64; i += 2) {
        const int e = (w[i] >> 7) & 0xFF;
        if (e < 100 || e > 134) return true;   // bf16 N(0,1) exps live in [100,134]
    }
    return false;
}
__device__ __forceinline__ bool detect_i64(const int* p) {
    for (int i = 1; i < 64; i += 2) if (p[i] != 0) return false;
    return true;
}
__device__ __forceinline__ bf16x8 load8(const void* p, int off, bool f32) {
    if (f32) {
        const float* q = (const float*)p + off;
        const f32x4 a = *(const f32x4*)q;
        const f32x4 b = *(const f32x4*)(q + 4);
        bf16x8 r;
        #pragma unroll
        for (int u = 0; u < 4; ++u) { r[u] = (bf16)a[u]; r[4 + u] = (bf16)b[u]; }
        return r;
    }
    return *(const bf16x8*)((const bf16*)p + off);
}
__device__ __forceinline__ float loadf(const void* p, int i, bool f32) {
    return f32 ? ((const float*)p)[i] : (float)((const bf16*)p)[i];
}
__device__ __forceinline__ void storef(void* p, int i, float v, bool f32) {
    if (f32) ((float*)p)[i] = v; else ((bf16*)p)[i] = (bf16)v;
}

// K0: one-time dtype detection -> flags (bit0: floats are fp32, bit1: ints are i64)
__global__ void detect_kernel(const void* nfeats, const int* dst, int* flags) {
    if (threadIdx.x == 0)
        flags[0] = (detect_f32(nfeats) ? 1 : 0) | (detect_i64(dst) ? 2 : 0);
}

// ---------------------------------------------------------------------------
// K1: bucket histogram via LDS (64 blocks) -> 65k global atomics instead of 800k
// ---------------------------------------------------------------------------
__global__ __launch_bounds__(256) void hist_kernel(
    const int* __restrict__ dst, const int* __restrict__ flags,
    int* __restrict__ count)
{
    __shared__ int h[BPAD];
    __shared__ int s_f;
    const int tid = threadIdx.x;
    if (tid == 0) s_f = flags[0];
    for (int i = tid; i < BPAD; i += 256) h[i] = 0;
    __syncthreads();
    const int ish = (s_f & 2) ? 1 : 0;
    for (int e = blockIdx.x * 256 + tid; e < N_EDGES; e += gridDim.x * 256)
        atomicAdd(&h[dst[e << ish] >> 5], 1);
    __syncthreads();
    for (int b = tid; b < BPAD; b += 256) {
        const int c = h[b];
        if (c) atomicAdd(&count[b], c);
    }
}

// ---------------------------------------------------------------------------
// K2: exclusive scan of 2048 counts (1024 thr x 2 elems) -> starts, cursor
// ---------------------------------------------------------------------------
__global__ __launch_bounds__(1024) void scan_kernel(
    const int* __restrict__ count, int* __restrict__ starts, int* __restrict__ cursor)
{
    __shared__ int s[1024];
    const int t = threadIdx.x;
    const int a = count[2 * t];
    const int b = count[2 * t + 1];
    const int own = a + b;
    s[t] = own;
    __syncthreads();
    for (int off = 1; off < 1024; off <<= 1) {
        int v = (t >= off) ? s[t - off] : 0;
        __syncthreads();
        s[t] += v;
        __syncthreads();
    }
    const int excl = s[t] - own;
    starts[2 * t]     = excl;
    starts[2 * t + 1] = excl + a;
    cursor[2 * t]     = excl;
    cursor[2 * t + 1] = excl + a;
}

// ---------------------------------------------------------------------------
// K3: two-pass scatter (64 blocks x 12500 edges). Pass 1: LDS hist. Reserve:
// one global atomic per (block,bucket). Pass 2: LDS-cursor scatter, writing
// uint2 { eid | local<<25 , src } — removes agg's src-chase level.
// ---------------------------------------------------------------------------
__global__ __launch_bounds__(256) void scatter_kernel(
    const int* __restrict__ src, const int* __restrict__ dst,
    const int* __restrict__ flags, int* __restrict__ cursor,
    uint2* __restrict__ sortedv)
{
    __shared__ int h[BPAD];
    __shared__ int s_f;
    const int tid = threadIdx.x;
    if (tid == 0) s_f = flags[0];
    for (int i = tid; i < BPAD; i += 256) h[i] = 0;
    __syncthreads();
    const int ish = (s_f & 2) ? 1 : 0;
    const int e0  = blockIdx.x * (N_EDGES / 64);   // 12500 per block, exact

    for (int i = tid; i < N_EDGES / 64; i += 256)
        atomicAdd(&h[dst[(e0 + i) << ish] >> 5], 1);
    __syncthreads();
    for (int b = tid; b < BPAD; b += 256) {
        const int c = h[b];
        h[b] = c ? atomicAdd(&cursor[b], c) : 0;   // h[b] becomes running cursor
    }
    __syncthreads();
    for (int i = tid; i < N_EDGES / 64; i += 256) {
        const int e = e0 + i;
        const int d = dst[e << ish];
        const int pos = atomicAdd(&h[d >> 5], 1);
        sortedv[pos] = make_uint2((unsigned)e | ((unsigned)(d & 31) << 25),
                                  (unsigned)src[e << ish]);
    }
}

// ---------------------------------------------------------------------------
// K4: fused message GEMM + LDS aggregation. One block = one 32-node bucket.
// Chain is now: sortedv (coalesced) -> feature gather (1 random level),
// 1-deep software pipeline, 3 blocks/CU (LDS ~53 KB).
// ---------------------------------------------------------------------------
__global__ __launch_bounds__(256) void agg_kernel(
    const void* __restrict__ nfeats,
    const void* __restrict__ efeats,
    const void* __restrict__ W_msg,
    const void* __restrict__ b_msg,
    const int*  __restrict__ flags,
    const int*  __restrict__ starts,
    const uint2* __restrict__ sortedv,
    bf16*       __restrict__ h_neigh)
{
    __shared__ float sH[33 * 133];     // 32 node rows + 1 dummy, stride 133
    __shared__ bf16  sWT[128 * 136];   // W_msg^T [n][k], stride 136
    __shared__ float sB[128];
    __shared__ int   s_f;

    const int tid = threadIdx.x;
    if (tid == 0) s_f = flags[0];
    for (int i = tid; i < 33 * 133; i += 256) sH[i] = 0.f;
    __syncthreads();
    const bool f32 = (s_f & 1) != 0;

    #pragma unroll
    for (int it = 0; it < 8; ++it) {   // stage W_msg^T (128x128)
        const int task = it * 256 + tid;
        const int k = task >> 4;
        const int c = task & 15;
        const bf16x8 w = load8(W_msg, k * 128 + c * 8, f32);
        #pragma unroll
        for (int u = 0; u < 8; ++u) sWT[(c * 8 + u) * 136 + k] = w[u];
    }
    if (tid < 128) sB[tid] = loadf(b_msg, tid, f32);
    __syncthreads();

    const int wave = tid >> 6;
    const int lane = tid & 63;
    const int m    = lane & 15;   // edge slot (B col / C col)
    const int quad = lane >> 4;   // k-group / C row group

    // hoist loop-invariant bias fragments (one f32x4 per t-tile)
    f32x4 bias[8];
    #pragma unroll
    for (int t = 0; t < 8; ++t)
        bias[t] = *(const f32x4*)(sB + t * 16 + quad * 4);

    const int bkt   = blockIdx.x;
    const int start = starts[bkt];
    const int end   = starts[bkt + 1];

    int i0 = start + wave * 16;
    if (i0 < end) {
        int idx = i0 + m;
        uint2 v = (idx < end) ? sortedv[idx] : make_uint2(SENTM, 0u);
        int eid   = v.x & 0xFFFFF;
        int local = v.x >> 25;
        int s     = (int)v.y;
        bf16x8 cf0 = load8(nfeats, s   * 64 +      quad * 8, f32);
        bf16x8 cf1 = load8(nfeats, s   * 64 + 32 + quad * 8, f32);
        bf16x8 cf2 = load8(efeats, eid * 64 +      quad * 8, f32);
        bf16x8 cf3 = load8(efeats, eid * 64 + 32 + quad * 8, f32);

        for (; i0 < end; i0 += 64) {
            // prefetch next group (sentinel-safe)
            const int idxn = i0 + 64 + m;
            const uint2 vn = (idxn < end) ? sortedv[idxn] : make_uint2(SENTM, 0u);
            const int eidn   = vn.x & 0xFFFFF;
            const int localn = vn.x >> 25;
            const int sn     = (int)vn.y;
            const bf16x8 nf0 = load8(nfeats, sn   * 64 +      quad * 8, f32);
            const bf16x8 nf1 = load8(nfeats, sn   * 64 + 32 + quad * 8, f32);
            const bf16x8 nf2 = load8(efeats, eidn * 64 +      quad * 8, f32);
            const bf16x8 nf3 = load8(efeats, eidn * 64 + 32 + quad * 8, f32);

            float* hp = &sH[local * 133];
            #pragma unroll
            for (int t = 0; t < 8; ++t) {
                f32x4 acc = bias[t];
                const bf16* ap = sWT + (t * 16 + m) * 136 + quad * 8;
                acc = __builtin_amdgcn_mfma_f32_16x16x32_bf16(*(const bf16x8*)(ap     ), cf0, acc, 0, 0, 0);
                acc = __builtin_amdgcn_mfma_f32_16x16x32_bf16(*(const bf16x8*)(ap + 32), cf1, acc, 0, 0, 0);
                acc = __builtin_amdgcn_mfma_f32_16x16x32_bf16(*(const bf16x8*)(ap + 64), cf2, acc, 0, 0, 0);
                acc = __builtin_amdgcn_mfma_f32_16x16x32_bf16(*(const bf16x8*)(ap + 96), cf3, acc, 0, 0, 0);
                #pragma unroll
                for (int i = 0; i < 4; ++i) {
                    const float val = acc[i];
                    if (val > 0.f)
                        atomicAdd(hp + t * 16 + quad * 4 + i, val);  // ds_add_f32
                }
            }
            cf0 = nf0; cf1 = nf1; cf2 = nf2; cf3 = nf3;
            local = localn;
        }
    }
    __syncthreads();

    // write bucket's h rows to global as bf16 (32 rows x 64 dword-pairs)
    const int base = bkt * NPB;
    for (int i = tid; i < NPB * 64; i += 256) {
        const int lrow  = i >> 6;
        const int dpair = i & 63;
        const int node  = base + lrow;
        if (node < N_NODES) {
            __hip_bfloat162 pv;
            pv.x = __float2bfloat16(sH[lrow * 133 + 2 * dpair]);
            pv.y = __float2bfloat16(sH[lrow * 133 + 2 * dpair + 1]);
            *(__hip_bfloat162*)(h_neigh + node * 128 + 2 * dpair) = pv;
        }
    }
}

// ---------------------------------------------------------------------------
// K5: out = relu([nfeats, h_neigh] @ W_apply + b_apply), K=192.
// ---------------------------------------------------------------------------
__global__ __launch_bounds__(256) void apply_kernel(
    const void* __restrict__ nfeats,
    const bf16* __restrict__ h_neigh,
    const void* __restrict__ W_apply,
    const void* __restrict__ b_apply,
    const int*  __restrict__ flags,
    void*       __restrict__ out)
{
    __shared__ bf16  sWT[128 * 200];   // [n][k], k<192, stride 200
    __shared__ float sB[128];
    __shared__ int s_f;

    const int tid = threadIdx.x;
    if (tid == 0) s_f = flags[0];
    __syncthreads();
    const bool f32 = (s_f & 1) != 0;

    #pragma unroll
    for (int it = 0; it < 12; ++it) {   // stage W_apply^T (192x128)
        const int task = it * 256 + tid;
        const int k = task >> 4;
        const int c = task & 15;
        const bf16x8 w = load8(W_apply, k * 128 + c * 8, f32);
        #pragma unroll
        for (int u = 0; u < 8; ++u) sWT[(c * 8 + u) * 200 + k] = w[u];
    }
    if (tid < 128) sB[tid] = loadf(b_apply, tid, f32);
    __syncthreads();

    const int wave = tid >> 6;
    const int lane = tid & 63;
    const int m    = lane & 15;
    const int quad = lane >> 4;

    const int nchunks = (N_NODES + 63) / 64;   // 782
    for (int chunk = blockIdx.x; chunk < nchunks; chunk += gridDim.x) {
        const int nbase = chunk * 64 + wave * 16;
        const int nm  = nbase + m;
        const int nmc = nm < N_NODES ? nm : N_NODES - 1;

        bf16x8 a[6];
        a[0] = load8(nfeats, nmc * 64 +      quad * 8, f32);
        a[1] = load8(nfeats, nmc * 64 + 32 + quad * 8, f32);
        #pragma unroll
        for (int kb = 0; kb < 4; ++kb)
            a[2 + kb] = *(const bf16x8*)(h_neigh + nmc * 128 + kb * 32 + quad * 8);

        #pragma unroll
        for (int t = 0; t < 8; ++t) {
            f32x4 acc = {0.f, 0.f, 0.f, 0.f};
            const bf16* bp = sWT + (t * 16 + m) * 200 + quad * 8;
            #pragma unroll
            for (int kb = 0; kb < 6; ++kb)
                acc = __builtin_amdgcn_mfma_f32_16x16x32_bf16(
                          a[kb], *(const bf16x8*)(bp + kb * 32), acc, 0, 0, 0);
            const int n = t * 16 + m;
            #pragma unroll
            for (int i = 0; i < 4; ++i) {
                const int row = nbase + quad * 4 + i;
                if (row < N_NODES) {
                    float v = acc[i] + sB[n];
                    v = v > 0.f ? v : 0.f;
                    storef(out, row * 128 + n, v, f32);
                }
            }
        }
    }
}

extern "C" void kernel_launch(void* const* d_in, const int* in_sizes, int n_in,
                              void* d_out, int out_size, void* d_ws, size_t ws_size,
                              hipStream_t stream) {
    const void* nfeats  = d_in[0];
    const void* efeats  = d_in[1];
    const void* W_msg   = d_in[2];
    const void* b_msg   = d_in[3];
    const void* W_apply = d_in[4];
    const void* b_apply = d_in[5];
    const int*  src     = (const int*)d_in[6];
    const int*  dst     = (const int*)d_in[7];

    // workspace layout (needs ~19.3 MB; round-2 proved ws >= 25.6 MB)
    char* ws = (char*)d_ws;
    bf16*  h_neigh = (bf16*)ws;                         // 12,800,000 B
    int*   count   = (int*)(ws + 12800000);             // 8 KB (2048)
    int*   starts  = (int*)(ws + 12800000 + 8192);      // 8 KB
    int*   cursor  = (int*)(ws + 12800000 + 16384);     // 8 KB
    int*   flags   = (int*)(ws + 12800000 + 24576);     // 64 B
    uint2* sortedv = (uint2*)(ws + 12800000 + 24640);   // 6.4 MB

    hipMemsetAsync(count, 0, BPAD * sizeof(int), stream);

    detect_kernel <<<1,    64,   0, stream>>>(nfeats, dst, flags);
    hist_kernel   <<<64,   256,  0, stream>>>(dst, flags, count);
    scan_kernel   <<<1,    1024, 0, stream>>>(count, starts, cursor);
    scatter_kernel<<<64,   256,  0, stream>>>(src, dst, flags, cursor, sortedv);
    agg_kernel    <<<NBKT, 256,  0, stream>>>(nfeats, efeats, W_msg, b_msg,
                                              flags, starts, sortedv, h_neigh);
    apply_kernel  <<<391,  256,  0, stream>>>(nfeats, h_neigh, W_apply, b_apply,
                                              flags, d_out);
}